// Round 5
// baseline (366.953 us; speedup 1.0000x reference)
//
#include <hip/hip_runtime.h>
#include <cmath>

#define NLEV 16
#define TSZ  (1u << 19)
#define TMASK (TSZ - 1u)
#define PR1 2654435761u
#define PR2 805459861u
#define NBUCK 32768   // 32^3 Morton buckets

struct LvlP {
    float    rf[NLEV];
    unsigned s1[NLEV];
    unsigned s2[NLEV];
};

// ---------- helpers ----------
static __device__ __forceinline__ unsigned part1by2(unsigned x) {
    x &= 0x3FFu;
    x = (x | (x << 16)) & 0x030000FFu;
    x = (x | (x << 8))  & 0x0300F00Fu;
    x = (x | (x << 4))  & 0x030C30C3u;
    x = (x | (x << 2))  & 0x09249249u;
    return x;
}
static __device__ __forceinline__ unsigned bucket_of(float x0, float x1, float x2) {
    unsigned bx = min(31u, (unsigned)(x0 * 32.0f));
    unsigned by = min(31u, (unsigned)(x1 * 32.0f));
    unsigned bz = min(31u, (unsigned)(x2 * 32.0f));
    return part1by2(bx) | (part1by2(by) << 1) | (part1by2(bz) << 2);
}
static __device__ __forceinline__ unsigned short f2bf(float f) { // RNE
    unsigned u = __float_as_uint(f);
    unsigned r = ((u >> 16) & 1u) + 0x7FFFu;
    return (unsigned short)((u + r) >> 16);
}
static __device__ __forceinline__ float bf2f(unsigned short h) {
    return __uint_as_float(((unsigned)h) << 16);
}

// ---------- sort pipeline ----------
__global__ __launch_bounds__(256) void zero_pos_kernel(unsigned* __restrict__ pos) {
    pos[blockIdx.x * 256 + threadIdx.x] = 0u;
}

__global__ __launch_bounds__(256) void hist_kernel(
    const float* __restrict__ xs, unsigned* __restrict__ pos, int n)
{
    int i = blockIdx.x * 256 + threadIdx.x;
    if (i >= n) return;
    unsigned b = bucket_of(xs[3 * i], xs[3 * i + 1], xs[3 * i + 2]);
    atomicAdd(&pos[b], 1u);
}

__global__ __launch_bounds__(256) void scanA_kernel(
    unsigned* __restrict__ pos, unsigned* __restrict__ bsum)
{
    __shared__ unsigned sh[256];
    int t = threadIdx.x;
    int g = blockIdx.x * 256 + t;
    unsigned v = pos[g];
    sh[t] = v;
    __syncthreads();
    for (int off = 1; off < 256; off <<= 1) {
        unsigned u = (t >= off) ? sh[t - off] : 0u;
        __syncthreads();
        sh[t] += u;
        __syncthreads();
    }
    pos[g] = sh[t] - v;
    if (t == 255) bsum[blockIdx.x] = sh[255];
}

__global__ __launch_bounds__(128) void scanB_kernel(unsigned* __restrict__ bsum)
{
    __shared__ unsigned sh[128];
    int t = threadIdx.x;
    unsigned v = bsum[t];
    sh[t] = v;
    __syncthreads();
    for (int off = 1; off < 128; off <<= 1) {
        unsigned u = (t >= off) ? sh[t - off] : 0u;
        __syncthreads();
        sh[t] += u;
        __syncthreads();
    }
    bsum[t] = sh[t] - v;
}

__global__ __launch_bounds__(256) void scanC_kernel(
    unsigned* __restrict__ pos, const unsigned* __restrict__ bsum)
{
    int g = blockIdx.x * 256 + threadIdx.x;
    pos[g] += bsum[blockIdx.x];
}

__global__ __launch_bounds__(256) void scatter_kernel(
    const float* __restrict__ xs, unsigned* __restrict__ pos,
    float4* __restrict__ S, int n)
{
    int i = blockIdx.x * 256 + threadIdx.x;
    if (i >= n) return;
    float x0 = xs[3 * i], x1 = xs[3 * i + 1], x2 = xs[3 * i + 2];
    unsigned b = bucket_of(x0, x1, x2);
    unsigned j = atomicAdd(&pos[b], 1u);
    S[j] = make_float4(x0, x1, x2, __uint_as_float((unsigned)i));
}

// ---------- encode: 2 points per thread (MLP), level-major, sorted ----------
struct PtState {
    float w0, w1, w2;
    float2 f[8];
};

static __device__ __forceinline__ void issue_gathers(
    float4 s4, float rf, unsigned st1, unsigned st2, bool dense, unsigned lbase,
    const float2* __restrict__ t2, const float4* __restrict__ t4, PtState& st)
{
    float s0 = s4.x * rf, s1f = s4.y * rf, s2f = s4.z * rf;
    float p0 = floorf(s0), p1 = floorf(s1f), p2 = floorf(s2f);
    st.w0 = s0 - p0; st.w1 = s1f - p1; st.w2 = s2f - p2;
    unsigned c0 = (unsigned)p0, c1 = (unsigned)p1, c2 = (unsigned)p2;
    #pragma unroll
    for (int p = 0; p < 4; ++p) {
        unsigned oy = (p >> 1) & 1u, oz = p & 1u;
        unsigned i0, i1;
        if (dense) {
            unsigned b = c0 + (c1 + oy) * st1 + (c2 + oz) * st2;
            i0 = b; i1 = b + 1u;
        } else {
            unsigned h = ((c1 + oy) * PR1) ^ ((c2 + oz) * PR2);
            i0 = (c0 ^ h) & TMASK;
            i1 = ((c0 + 1u) ^ h) & TMASK;
        }
        float2 fa, fb;
        if ((i0 ^ i1) == 1u) {
            float4 v = t4[(lbase + (i0 & ~1u)) >> 1];
            if (i0 & 1u) { fa = make_float2(v.z, v.w); fb = make_float2(v.x, v.y); }
            else         { fa = make_float2(v.x, v.y); fb = make_float2(v.z, v.w); }
        } else {
            fa = t2[lbase + i0];
            fb = t2[lbase + i1];
        }
        st.f[p] = fa;
        st.f[p + 4] = fb;
    }
}

static __device__ __forceinline__ ushort2 reduce_point(const PtState& st)
{
    float i0w = 1.f - st.w0, i1w = 1.f - st.w1, i2w = 1.f - st.w2;
    float acc0 = 0.f, acc1 = 0.f;
    #pragma unroll
    for (int k = 0; k < 8; ++k) {
        float wa = ((k >> 2) & 1) ? st.w0 : i0w;
        float wb = ((k >> 1) & 1) ? st.w1 : i1w;
        float wcv = (k & 1) ? st.w2 : i2w;
        float wk = (wa * wb) * wcv;
        acc0 = fmaf(wk, st.f[k].x, acc0);
        acc1 = fmaf(wk, st.f[k].y, acc1);
    }
    return make_ushort2(f2bf(acc0), f2bf(acc1));
}

__global__ __launch_bounds__(256) void enc_sorted2_kernel(
    const float4* __restrict__ S, const float* __restrict__ table,
    ushort2* __restrict__ F, int n, int C2, LvlP lp)
{
    int bid = blockIdx.x;
    int l = bid / C2;
    int chunk = bid - l * C2;
    int j0 = chunk * 512 + (int)threadIdx.x;
    int j1 = j0 + 256;

    const float2* __restrict__ t2 = (const float2*)table;
    const float4* __restrict__ t4 = (const float4*)table;
    float rf = lp.rf[l];
    unsigned st1 = lp.s1[l], st2 = lp.s2[l];
    bool dense = (l < 7);
    unsigned lbase = (unsigned)l << 19;

    bool vA = (j0 < n), vB = (j1 < n);
    float4 sA = vA ? S[j0] : make_float4(0.f, 0.f, 0.f, 0.f);
    float4 sB = vB ? S[j1] : make_float4(0.f, 0.f, 0.f, 0.f);

    PtState stA, stB;
    issue_gathers(sA, rf, st1, st2, dense, lbase, t2, t4, stA);
    issue_gathers(sB, rf, st1, st2, dense, lbase, t2, t4, stB);

    if (vA) F[(size_t)l * n + j0] = reduce_point(stA);
    if (vB) F[(size_t)l * n + j1] = reduce_point(stB);
}

// ---------- transpose + scatter to original order ----------
__global__ __launch_bounds__(256) void tr_scatter_kernel(
    const ushort2* __restrict__ F, const float4* __restrict__ S,
    float4* __restrict__ out4, int n)
{
    __shared__ ushort2 tile[16][65];
    __shared__ unsigned sorig[64];
    int t = threadIdx.x;
    int base = blockIdx.x * 64;
    int p  = t & 63;
    int l0 = t >> 6;
    #pragma unroll
    for (int r = 0; r < 4; ++r) {
        int l = l0 * 4 + r;
        int gi = base + p;
        if (gi < n) tile[l][p] = F[(size_t)l * n + gi];
    }
    if (t < 64 && base + t < n) sorig[t] = __float_as_uint(S[base + t].w);
    __syncthreads();
    #pragma unroll
    for (int r = 0; r < 2; ++r) {
        int idx = t + 256 * r;
        int pp = idx >> 3;
        int q  = idx & 7;
        int gi = base + pp;
        if (gi < n) {
            ushort2 a = tile[2 * q][pp];
            ushort2 b = tile[2 * q + 1][pp];
            out4[(size_t)sorig[pp] * 8 + q] =
                make_float4(bf2f(a.x), bf2f(a.y), bf2f(b.x), bf2f(b.y));
        }
    }
}

// ---------- fallback: point-major ----------
__global__ __launch_bounds__(256) void hashenc_kernel(
    const float* __restrict__ xs, const float* __restrict__ table,
    float* __restrict__ out, int n, LvlP lp)
{
    int i = blockIdx.x * 256 + threadIdx.x;
    if (i >= n) return;
    float x0 = xs[3 * i], x1 = xs[3 * i + 1], x2 = xs[3 * i + 2];
    const float2* __restrict__ t2 = (const float2*)table;
    float2* __restrict__ o2 = (float2*)out;
    #pragma unroll
    for (int l = 0; l < NLEV; ++l) {
        float rf = lp.rf[l];
        float s0 = x0 * rf, s1f = x1 * rf, s2f = x2 * rf;
        float p0 = floorf(s0), p1 = floorf(s1f), p2 = floorf(s2f);
        float w0 = s0 - p0, w1 = s1f - p1, w2 = s2f - p2;
        unsigned c0 = (unsigned)p0, c1 = (unsigned)p1, c2 = (unsigned)p2;
        float2 f[8];
        #pragma unroll
        for (int k = 0; k < 8; ++k) {
            unsigned a0 = c0 + ((k >> 2) & 1u), a1 = c1 + ((k >> 1) & 1u), a2 = c2 + (k & 1u);
            unsigned id;
            if (l < 7) id = a0 + a1 * lp.s1[l] + a2 * lp.s2[l];
            else       id = (a0 ^ (a1 * PR1) ^ (a2 * PR2)) & TMASK;
            f[k] = t2[((unsigned)l << 19) + id];
        }
        float i0 = 1.f - w0, i1 = 1.f - w1, i2 = 1.f - w2;
        float acc0 = 0.f, acc1 = 0.f;
        #pragma unroll
        for (int k = 0; k < 8; ++k) {
            float wa = ((k >> 2) & 1) ? w0 : i0;
            float wb = ((k >> 1) & 1) ? w1 : i1;
            float wcv = (k & 1) ? w2 : i2;
            float wk = (wa * wb) * wcv;
            acc0 = fmaf(wk, f[k].x, acc0);
            acc1 = fmaf(wk, f[k].y, acc1);
        }
        o2[(size_t)i * 16 + l] = make_float2(acc0, acc1);
    }
}

extern "C" void kernel_launch(void* const* d_in, const int* in_sizes, int n_in,
                              void* d_out, int out_size, void* d_ws, size_t ws_size,
                              hipStream_t stream)
{
    const float* xs    = (const float*)d_in[0];
    const float* table = (const float*)d_in[1];
    float* out = (float*)d_out;
    int n = in_sizes[0] / 3;

    // Replicate numpy's resolution computation exactly (same libm, same machine)
    LvlP lp;
    double B = exp((log(512.0) - log(16.0)) / 15.0);
    for (int l = 0; l < NLEV; ++l) {
        double rd;
        if (l == 0)      rd = 16.0;
        else if (l == 1) rd = floor(16.0 * B);
        else if (l == 2) rd = floor(16.0 * (B * B));
        else             rd = floor(16.0 * pow(B, (double)l));
        unsigned r = (unsigned)rd;
        lp.rf[l] = (float)r;
        lp.s1[l] = r + 1u;
        lp.s2[l] = (r + 1u) * (r + 1u);
    }

    int C = (n + 255) / 256;
    int C2 = (n + 511) / 512;
    size_t posB  = (size_t)NBUCK * 4;
    size_t bsumB = 1024;
    size_t sB    = (size_t)n * 16;
    size_t fB    = (size_t)NLEV * (size_t)n * 4;
    size_t need  = posB + bsumB + sB + fB;

    if (ws_size >= need) {
        char* wsc = (char*)d_ws;
        unsigned* pos  = (unsigned*)wsc;
        unsigned* bsum = (unsigned*)(wsc + posB);
        float4*   S    = (float4*)(wsc + posB + bsumB);
        ushort2*  F    = (ushort2*)(wsc + posB + bsumB + sB);

        zero_pos_kernel<<<NBUCK / 256, 256, 0, stream>>>(pos);
        hist_kernel<<<C, 256, 0, stream>>>(xs, pos, n);
        scanA_kernel<<<NBUCK / 256, 256, 0, stream>>>(pos, bsum);
        scanB_kernel<<<1, 128, 0, stream>>>(bsum);
        scanC_kernel<<<NBUCK / 256, 256, 0, stream>>>(pos, bsum);
        scatter_kernel<<<C, 256, 0, stream>>>(xs, pos, S, n);
        enc_sorted2_kernel<<<16 * C2, 256, 0, stream>>>(S, table, F, n, C2, lp);
        tr_scatter_kernel<<<(n + 63) / 64, 256, 0, stream>>>(F, S, (float4*)out, n);
    } else {
        hashenc_kernel<<<C, 256, 0, stream>>>(xs, table, out, n, lp);
    }
}

// Round 6
// 353.760 us; speedup vs baseline: 1.0373x; 1.0373x over previous
//
#include <hip/hip_runtime.h>
#include <cmath>

#define NLEV 16
#define TSZ  (1u << 19)
#define TMASK (TSZ - 1u)
#define PR1 2654435761u
#define PR2 805459861u
#define NBUCK 32768   // 32^3 Morton buckets

struct LvlP {
    float    rf[NLEV];
    unsigned s1[NLEV];
    unsigned s2[NLEV];
};

// ---------- helpers ----------
static __device__ __forceinline__ unsigned part1by2(unsigned x) {
    x &= 0x3FFu;
    x = (x | (x << 16)) & 0x030000FFu;
    x = (x | (x << 8))  & 0x0300F00Fu;
    x = (x | (x << 4))  & 0x030C30C3u;
    x = (x | (x << 2))  & 0x09249249u;
    return x;
}
static __device__ __forceinline__ unsigned bucket_of(float x0, float x1, float x2) {
    unsigned bx = min(31u, (unsigned)(x0 * 32.0f));
    unsigned by = min(31u, (unsigned)(x1 * 32.0f));
    unsigned bz = min(31u, (unsigned)(x2 * 32.0f));
    return part1by2(bx) | (part1by2(by) << 1) | (part1by2(bz) << 2);
}
static __device__ __forceinline__ unsigned short f2bf(float f) { // RNE
    unsigned u = __float_as_uint(f);
    unsigned r = ((u >> 16) & 1u) + 0x7FFFu;
    return (unsigned short)((u + r) >> 16);
}
static __device__ __forceinline__ float bf2f(unsigned short h) {
    return __uint_as_float(((unsigned)h) << 16);
}

// ---------- sort pipeline ----------
__global__ __launch_bounds__(256) void zero_pos_kernel(unsigned* __restrict__ pos) {
    pos[blockIdx.x * 256 + threadIdx.x] = 0u;
}

__global__ __launch_bounds__(256) void hist_kernel(
    const float* __restrict__ xs, unsigned* __restrict__ pos, int n)
{
    int i = blockIdx.x * 256 + threadIdx.x;
    if (i >= n) return;
    unsigned b = bucket_of(xs[3 * i], xs[3 * i + 1], xs[3 * i + 2]);
    atomicAdd(&pos[b], 1u);
}

__global__ __launch_bounds__(256) void scanA_kernel(
    unsigned* __restrict__ pos, unsigned* __restrict__ bsum)
{
    __shared__ unsigned sh[256];
    int t = threadIdx.x;
    int g = blockIdx.x * 256 + t;
    unsigned v = pos[g];
    sh[t] = v;
    __syncthreads();
    for (int off = 1; off < 256; off <<= 1) {
        unsigned u = (t >= off) ? sh[t - off] : 0u;
        __syncthreads();
        sh[t] += u;
        __syncthreads();
    }
    pos[g] = sh[t] - v;
    if (t == 255) bsum[blockIdx.x] = sh[255];
}

__global__ __launch_bounds__(128) void scanB_kernel(unsigned* __restrict__ bsum)
{
    __shared__ unsigned sh[128];
    int t = threadIdx.x;
    unsigned v = bsum[t];
    sh[t] = v;
    __syncthreads();
    for (int off = 1; off < 128; off <<= 1) {
        unsigned u = (t >= off) ? sh[t - off] : 0u;
        __syncthreads();
        sh[t] += u;
        __syncthreads();
    }
    bsum[t] = sh[t] - v;
}

__global__ __launch_bounds__(256) void scanC_kernel(
    unsigned* __restrict__ pos, const unsigned* __restrict__ bsum)
{
    int g = blockIdx.x * 256 + threadIdx.x;
    pos[g] += bsum[blockIdx.x];
}

__global__ __launch_bounds__(256) void scatter_kernel(
    const float* __restrict__ xs, unsigned* __restrict__ pos,
    float4* __restrict__ S, int n)
{
    int i = blockIdx.x * 256 + threadIdx.x;
    if (i >= n) return;
    float x0 = xs[3 * i], x1 = xs[3 * i + 1], x2 = xs[3 * i + 2];
    unsigned b = bucket_of(x0, x1, x2);
    unsigned j = atomicAdd(&pos[b], 1u);
    S[j] = make_float4(x0, x1, x2, __uint_as_float((unsigned)i));
}

// ---------- per-level encode core: 2-issue-slot pair loads ----------
// Pair (c0, c0+1) along x. Load the aligned float4 covering idx(c0) (always
// serves corner c0; serves c0+1 too when co-resident). Predicated 2nd float4
// only for lanes whose pair straddles an alignment boundary.
template <bool DENSE>
static __device__ __forceinline__ ushort2 enc_one(
    float x0, float x1, float x2, float rf, unsigned st1, unsigned st2,
    unsigned lbase, const float4* __restrict__ t4)
{
    float s0 = x0 * rf, s1f = x1 * rf, s2f = x2 * rf;
    float p0 = floorf(s0), p1 = floorf(s1f), p2 = floorf(s2f);
    float w0 = s0 - p0, w1 = s1f - p1, w2 = s2f - p2;
    unsigned c0 = (unsigned)p0, c1 = (unsigned)p1, c2 = (unsigned)p2;

    float2 f[8];
    #pragma unroll
    for (int p = 0; p < 4; ++p) {
        unsigned oy = (p >> 1) & 1u, oz = p & 1u;
        unsigned q0, q1;
        if (DENSE) {
            unsigned b = c0 + (c1 + oy) * st1 + (c2 + oz) * st2;
            q0 = b; q1 = b + 1u;
        } else {
            unsigned h = ((c1 + oy) * PR1) ^ ((c2 + oz) * PR2);
            q0 = (h ^ c0) & TMASK;
            q1 = (h ^ (c0 + 1u)) & TMASK;
        }
        float4 v0 = t4[(lbase + (q0 & ~1u)) >> 1];
        float2 e0 = make_float2(v0.x, v0.y), e1 = make_float2(v0.z, v0.w);
        float2 fa = (q0 & 1u) ? e1 : e0;
        // pair co-resident in v0?  dense: q1==q0+1 in same f4 iff q0 even;
        // hashed: q1==q0^1 (same f4 always) iff c0 even.
        bool one = DENSE ? ((q0 & 1u) == 0u) : ((c0 & 1u) == 0u);
        float2 fb;
        if (one) {
            fb = (q0 & 1u) ? e0 : e1;
        } else {
            float4 v1 = t4[(lbase + (q1 & ~1u)) >> 1];
            fb = (q1 & 1u) ? make_float2(v1.z, v1.w) : make_float2(v1.x, v1.y);
        }
        f[p] = fa;
        f[p + 4] = fb;
    }

    float i0w = 1.f - w0, i1w = 1.f - w1, i2w = 1.f - w2;
    float acc0 = 0.f, acc1 = 0.f;
    #pragma unroll
    for (int k = 0; k < 8; ++k) {
        float wa = ((k >> 2) & 1) ? w0 : i0w;
        float wb = ((k >> 1) & 1) ? w1 : i1w;
        float wcv = (k & 1) ? w2 : i2w;
        float wk = (wa * wb) * wcv;
        acc0 = fmaf(wk, f[k].x, acc0);
        acc1 = fmaf(wk, f[k].y, acc1);
    }
    return make_ushort2(f2bf(acc0), f2bf(acc1));
}

// ---------- encode: unit 0 = dense levels 0-6 fused; units 1-9 = levels 7-15
__global__ __launch_bounds__(256) void enc_kernel(
    const float4* __restrict__ S, const float* __restrict__ table,
    ushort2* __restrict__ F, int n, int C, LvlP lp)
{
    int bid = blockIdx.x;
    int u = bid / C;
    int chunk = bid - u * C;
    int j = chunk * 256 + (int)threadIdx.x;
    if (j >= n) return;

    float4 s4 = S[j];
    float x0 = s4.x, x1 = s4.y, x2 = s4.z;
    const float4* __restrict__ t4 = (const float4*)table;

    if (u == 0) {
        #pragma unroll
        for (int l = 0; l < 7; ++l) {
            ushort2 r = enc_one<true>(x0, x1, x2, lp.rf[l], lp.s1[l], lp.s2[l],
                                      (unsigned)l << 19, t4);
            F[(size_t)l * n + j] = r;
        }
    } else {
        int l = u + 6;
        ushort2 r = enc_one<false>(x0, x1, x2, lp.rf[l], 0u, 0u,
                                   (unsigned)l << 19, t4);
        F[(size_t)l * n + j] = r;
    }
}

// ---------- transpose + scatter to original order ----------
__global__ __launch_bounds__(256) void tr_scatter_kernel(
    const ushort2* __restrict__ F, const float4* __restrict__ S,
    float4* __restrict__ out4, int n)
{
    __shared__ ushort2 tile[16][65];
    __shared__ unsigned sorig[64];
    int t = threadIdx.x;
    int base = blockIdx.x * 64;
    int p  = t & 63;
    int l0 = t >> 6;
    #pragma unroll
    for (int r = 0; r < 4; ++r) {
        int l = l0 * 4 + r;
        int gi = base + p;
        if (gi < n) tile[l][p] = F[(size_t)l * n + gi];
    }
    if (t < 64 && base + t < n) sorig[t] = __float_as_uint(S[base + t].w);
    __syncthreads();
    #pragma unroll
    for (int r = 0; r < 2; ++r) {
        int idx = t + 256 * r;
        int pp = idx >> 3;
        int q  = idx & 7;
        int gi = base + pp;
        if (gi < n) {
            ushort2 a = tile[2 * q][pp];
            ushort2 b = tile[2 * q + 1][pp];
            out4[(size_t)sorig[pp] * 8 + q] =
                make_float4(bf2f(a.x), bf2f(a.y), bf2f(b.x), bf2f(b.y));
        }
    }
}

// ---------- fallback: point-major ----------
__global__ __launch_bounds__(256) void hashenc_kernel(
    const float* __restrict__ xs, const float* __restrict__ table,
    float* __restrict__ out, int n, LvlP lp)
{
    int i = blockIdx.x * 256 + threadIdx.x;
    if (i >= n) return;
    float x0 = xs[3 * i], x1 = xs[3 * i + 1], x2 = xs[3 * i + 2];
    const float2* __restrict__ t2 = (const float2*)table;
    float2* __restrict__ o2 = (float2*)out;
    #pragma unroll
    for (int l = 0; l < NLEV; ++l) {
        float rf = lp.rf[l];
        float s0 = x0 * rf, s1f = x1 * rf, s2f = x2 * rf;
        float p0 = floorf(s0), p1 = floorf(s1f), p2 = floorf(s2f);
        float w0 = s0 - p0, w1 = s1f - p1, w2 = s2f - p2;
        unsigned c0 = (unsigned)p0, c1 = (unsigned)p1, c2 = (unsigned)p2;
        float2 f[8];
        #pragma unroll
        for (int k = 0; k < 8; ++k) {
            unsigned a0 = c0 + ((k >> 2) & 1u), a1 = c1 + ((k >> 1) & 1u), a2 = c2 + (k & 1u);
            unsigned id;
            if (l < 7) id = a0 + a1 * lp.s1[l] + a2 * lp.s2[l];
            else       id = (a0 ^ (a1 * PR1) ^ (a2 * PR2)) & TMASK;
            f[k] = t2[((unsigned)l << 19) + id];
        }
        float i0 = 1.f - w0, i1 = 1.f - w1, i2 = 1.f - w2;
        float acc0 = 0.f, acc1 = 0.f;
        #pragma unroll
        for (int k = 0; k < 8; ++k) {
            float wa = ((k >> 2) & 1) ? w0 : i0;
            float wb = ((k >> 1) & 1) ? w1 : i1;
            float wcv = (k & 1) ? w2 : i2;
            float wk = (wa * wb) * wcv;
            acc0 = fmaf(wk, f[k].x, acc0);
            acc1 = fmaf(wk, f[k].y, acc1);
        }
        o2[(size_t)i * 16 + l] = make_float2(acc0, acc1);
    }
}

extern "C" void kernel_launch(void* const* d_in, const int* in_sizes, int n_in,
                              void* d_out, int out_size, void* d_ws, size_t ws_size,
                              hipStream_t stream)
{
    const float* xs    = (const float*)d_in[0];
    const float* table = (const float*)d_in[1];
    float* out = (float*)d_out;
    int n = in_sizes[0] / 3;

    // Replicate numpy's resolution computation exactly (same libm, same machine)
    LvlP lp;
    double B = exp((log(512.0) - log(16.0)) / 15.0);
    for (int l = 0; l < NLEV; ++l) {
        double rd;
        if (l == 0)      rd = 16.0;
        else if (l == 1) rd = floor(16.0 * B);
        else if (l == 2) rd = floor(16.0 * (B * B));
        else             rd = floor(16.0 * pow(B, (double)l));
        unsigned r = (unsigned)rd;
        lp.rf[l] = (float)r;
        lp.s1[l] = r + 1u;
        lp.s2[l] = (r + 1u) * (r + 1u);
    }

    int C = (n + 255) / 256;
    size_t posB  = (size_t)NBUCK * 4;
    size_t bsumB = 1024;
    size_t sB    = (size_t)n * 16;
    size_t fB    = (size_t)NLEV * (size_t)n * 4;
    size_t need  = posB + bsumB + sB + fB;

    if (ws_size >= need) {
        char* wsc = (char*)d_ws;
        unsigned* pos  = (unsigned*)wsc;
        unsigned* bsum = (unsigned*)(wsc + posB);
        float4*   S    = (float4*)(wsc + posB + bsumB);
        ushort2*  F    = (ushort2*)(wsc + posB + bsumB + sB);

        zero_pos_kernel<<<NBUCK / 256, 256, 0, stream>>>(pos);
        hist_kernel<<<C, 256, 0, stream>>>(xs, pos, n);
        scanA_kernel<<<NBUCK / 256, 256, 0, stream>>>(pos, bsum);
        scanB_kernel<<<1, 128, 0, stream>>>(bsum);
        scanC_kernel<<<NBUCK / 256, 256, 0, stream>>>(pos, bsum);
        scatter_kernel<<<C, 256, 0, stream>>>(xs, pos, S, n);
        enc_kernel<<<10 * C, 256, 0, stream>>>(S, table, F, n, C, lp);
        tr_scatter_kernel<<<(n + 63) / 64, 256, 0, stream>>>(F, S, (float4*)out, n);
    } else {
        hashenc_kernel<<<C, 256, 0, stream>>>(xs, table, out, n, lp);
    }
}